// Round 1
// baseline (701.028 us; speedup 1.0000x reference)
//
#include <hip/hip_runtime.h>

#define DEV_INLINE __device__ __forceinline__

// Problem constants (B,L,E,H,HD) = (2,256,512,8,64)
static constexpr int Bb = 2, Ls = 256, E = 512, H = 8;
static constexpr int BL = Bb * Ls;  // 512

// workspace layout in floats
static constexpr size_t WS_QP = 0;
static constexpr size_t WS_KP = WS_QP + (size_t)BL * E;       // 262144
static constexpr size_t WS_VP = WS_KP + (size_t)BL * E;
static constexpr size_t WS_M  = WS_VP + (size_t)BL * E;       // BL*H*E = 2097152
static constexpr size_t WS_C  = WS_M  + (size_t)BL * H * E;   // 4096
static constexpr size_t WS_O  = WS_C  + (size_t)BL * H;       // 262144
// total = 3,149,824 floats = 12.6 MB

DEV_INLINE float dot4f(float4 a, float4 b) {
  return a.x * b.x + a.y * b.y + a.z * b.z + a.w * b.w;
}

// ---------------- generic 64x64 fp32 tiled GEMM core ----------------
// C[i,j] = sum_k A[i,k] * B[k,j]            (TRANSB==0)
// C[i,j] = sum_k A[i,k] * B[j,k]  (+bias)   (TRANSB==1)
// grid: (x = col tiles, y = row tiles); block 256; dims multiples of 64.
template <int TRANSB>
DEV_INLINE void gemm_tile(const float* __restrict__ A, int lda,
                          const float* __restrict__ B, int ldb,
                          float* __restrict__ C, int ldc, int Ksz,
                          const float* __restrict__ bias) {
  __shared__ float As[16][68];
  __shared__ float Bs[16][68];
  const int t = threadIdx.x;
  const int tx = t & 15, ty = t >> 4;
  const int i0 = blockIdx.y * 64, j0 = blockIdx.x * 64;
  float acc[4][4] = {};
  for (int k0 = 0; k0 < Ksz; k0 += 16) {
    {
      const int ka = t & 15, ia = t >> 4;
#pragma unroll
      for (int r = 0; r < 4; ++r)
        As[ka][ia + 16 * r] = A[(size_t)(i0 + ia + 16 * r) * lda + (k0 + ka)];
    }
    if (TRANSB == 0) {
      const int jb = t & 63, kb = t >> 6;
#pragma unroll
      for (int r = 0; r < 4; ++r)
        Bs[kb + 4 * r][jb] = B[(size_t)(k0 + kb + 4 * r) * ldb + (j0 + jb)];
    } else {
      const int kb = t & 15, jb = t >> 4;
#pragma unroll
      for (int r = 0; r < 4; ++r)
        Bs[kb][jb + 16 * r] = B[(size_t)(j0 + jb + 16 * r) * ldb + (k0 + kb)];
    }
    __syncthreads();
#pragma unroll
    for (int kk = 0; kk < 16; ++kk) {
      float4 a4 = *(const float4*)&As[kk][ty * 4];
      float4 b4 = *(const float4*)&Bs[kk][tx * 4];
      acc[0][0] += a4.x * b4.x; acc[0][1] += a4.x * b4.y;
      acc[0][2] += a4.x * b4.z; acc[0][3] += a4.x * b4.w;
      acc[1][0] += a4.y * b4.x; acc[1][1] += a4.y * b4.y;
      acc[1][2] += a4.y * b4.z; acc[1][3] += a4.y * b4.w;
      acc[2][0] += a4.z * b4.x; acc[2][1] += a4.z * b4.y;
      acc[2][2] += a4.z * b4.z; acc[2][3] += a4.z * b4.w;
      acc[3][0] += a4.w * b4.x; acc[3][1] += a4.w * b4.y;
      acc[3][2] += a4.w * b4.z; acc[3][3] += a4.w * b4.w;
    }
    __syncthreads();
  }
#pragma unroll
  for (int r = 0; r < 4; ++r) {
#pragma unroll
    for (int c2 = 0; c2 < 4; ++c2) {
      float v = acc[r][c2];
      if (bias) v += bias[j0 + tx * 4 + c2];
      C[(size_t)(i0 + ty * 4 + r) * ldc + (j0 + tx * 4 + c2)] = v;
    }
  }
}

// K1: qp = query@Wq, kp = key@Wk, vp = value@Wq  (bug preserved: vp uses Wq)
__global__ __launch_bounds__(256) void k1_proj(
    const float* __restrict__ q, const float* __restrict__ k,
    const float* __restrict__ v, const float* __restrict__ Wq,
    const float* __restrict__ Wk, float* __restrict__ qp,
    float* __restrict__ kp, float* __restrict__ vp) {
  const float* A; const float* Bm; float* C;
  switch (blockIdx.z) {
    case 0:  A = q; Bm = Wq; C = qp; break;
    case 1:  A = k; Bm = Wk; C = kp; break;
    default: A = v; Bm = Wq; C = vp; break;
  }
  gemm_tile<0>(A, 512, Bm, 512, C, 512, 512, nullptr);
}

// K2: M[bk, h, e] = sum_d kp[bk, h*64+d] * Wr[h*64+d, e]   (GEMM per head h=z)
__global__ __launch_bounds__(256) void k2_M(const float* __restrict__ kp,
                                            const float* __restrict__ Wr,
                                            float* __restrict__ M) {
  const int h = blockIdx.z;
  gemm_tile<0>(kp + h * 64, 512, Wr + (size_t)h * 64 * 512, 512,
               M + (size_t)h * 512, 4096, 64, nullptr);
}

// K2b: c[bk, h] = sum_d br[h*64+d] * kp[bk, h*64+d]
__global__ __launch_bounds__(256) void k2b_c(const float* __restrict__ kp,
                                             const float* __restrict__ br,
                                             float* __restrict__ c) {
  int idx = blockIdx.x * 256 + threadIdx.x;  // 4096 total
  int bk = idx >> 3, h = idx & 7;
  float s = 0.f;
#pragma unroll 8
  for (int d = 0; d < 64; ++d)
    s += br[h * 64 + d] * kp[(size_t)bk * 512 + h * 64 + d];
  c[idx] = s;
}

// K3: logits[b,q,k,h] = qp[b,q,h,:].kp[b,k,h,:] + c[b,k,h]
// block per (b,q); each wave handles k rows strided by 4.
__global__ __launch_bounds__(256) void k3_qk(const float* __restrict__ qp,
                                             const float* __restrict__ kp,
                                             const float* __restrict__ c,
                                             float* __restrict__ logits) {
  const int bq = blockIdx.x;
  const int b = bq >> 8;
  __shared__ float qrow[512];
  const int t = threadIdx.x;
  if (t < 128)
    ((float4*)qrow)[t] = ((const float4*)(qp + (size_t)bq * 512))[t];
  __syncthreads();
  const int w = t >> 6, es = t & 63;
  const int g = es >> 4;  // head group: first half -> h=g, second -> h=4+g
  float4 q1 = *(const float4*)&qrow[4 * es];
  float4 q2 = *(const float4*)&qrow[256 + 4 * es];
  for (int k = w; k < 256; k += 4) {
    const float4* kr = (const float4*)(kp + ((size_t)b * 256 + k) * 512);
    float4 k1 = kr[es], k2 = kr[64 + es];
    float s1 = dot4f(q1, k1);
    float s2 = dot4f(q2, k2);
#pragma unroll
    for (int off = 8; off >= 1; off >>= 1) {
      s1 += __shfl_down(s1, off, 16);
      s2 += __shfl_down(s2, off, 16);
    }
    if ((es & 15) == 0) {
      float* L = logits + (((size_t)bq) * 256 + k) * 8;
      const float* cc = c + ((size_t)b * 256 + k) * 8;
      L[g] = s1 + cc[g];
      L[4 + g] = s2 + cc[4 + g];
    }
  }
}

// K4 (hot): logits[b,q,k,h] += sum_e rel[b,q,k,e] * M[b,k,h,e]
// block per (b,k). Lane (h = lane>>3, s = lane&7) caches M[b,k,h,64s..64s+64)
// in 16 float4 regs; relation rows are streamed (each element read from HBM
// exactly once device-wide), reduced over s via 3 shfl_xor.
__global__ __launch_bounds__(256) void k4_rel(const float* __restrict__ rel,
                                              const float* __restrict__ Mw,
                                              float* __restrict__ logits) {
  const int bk = blockIdx.x;
  const int b = bk >> 8, k = bk & 255;
  const int t = threadIdx.x, w = t >> 6, lane = t & 63;
  const int h = lane >> 3, s = lane & 7;
  const float4* M4 =
      (const float4*)(Mw + (((size_t)bk * 8) + h) * 512 + 64 * s);
  float4 m[16];
#pragma unroll
  for (int i = 0; i < 16; ++i) m[i] = M4[i];
  for (int q = w; q < 256; q += 4) {
    const float4* R =
        ((const float4*)(rel + (((size_t)b * 256 + q) * 256 + k) * 512)) +
        16 * s;
    float acc = 0.f;
#pragma unroll
    for (int i = 0; i < 16; ++i) acc += dot4f(R[i], m[i]);
    acc += __shfl_xor(acc, 1);
    acc += __shfl_xor(acc, 2);
    acc += __shfl_xor(acc, 4);
    if (s == 0) {
      float* L = logits + (((size_t)b * 256 + q) * 256 + k) * 8 + h;
      *L = *L + acc;
    }
  }
}

// K5: softmax over k per (b,q,h); writes normalized a in place (d_out region),
// then o[b,q,:] = sum_k a[k,h] * vp[b,k,:]
__global__ __launch_bounds__(256) void k5_softmax(float* __restrict__ logits,
                                                  const float* __restrict__ vp,
                                                  float* __restrict__ o) {
  const int bq = blockIdx.x;
  const int b = bq >> 8;
  const int t = threadIdx.x;
  float* L = logits + (size_t)bq * 2048;
  float4 x0 = ((float4*)L)[t * 2];
  float4 x1 = ((float4*)L)[t * 2 + 1];
  float x[8] = {x0.x, x0.y, x0.z, x0.w, x1.x, x1.y, x1.z, x1.w};
  const float SCALE = 0.125f;  // 1/sqrt(64)
#pragma unroll
  for (int j = 0; j < 8; ++j) x[j] *= SCALE;

  __shared__ float tr[8][272];  // [h][k], stride 272 -> conflict-free
  __shared__ float mx[8], sm[8];
#pragma unroll
  for (int hh = 0; hh < 8; ++hh) tr[hh][t] = x[hh];
  __syncthreads();
  const int g = t >> 5, j = t & 31;
  float m = -1e30f;
#pragma unroll
  for (int i = 0; i < 8; ++i) m = fmaxf(m, tr[g][j + 32 * i]);
#pragma unroll
  for (int off = 16; off >= 1; off >>= 1) m = fmaxf(m, __shfl_down(m, off, 32));
  if (j == 0) mx[g] = m;
  __syncthreads();
  float p[8];
#pragma unroll
  for (int hh = 0; hh < 8; ++hh) p[hh] = __expf(x[hh] - mx[hh]);
#pragma unroll
  for (int hh = 0; hh < 8; ++hh) tr[hh][t] = p[hh];
  __syncthreads();
  float ss = 0.f;
#pragma unroll
  for (int i = 0; i < 8; ++i) ss += tr[g][j + 32 * i];
#pragma unroll
  for (int off = 16; off >= 1; off >>= 1) ss += __shfl_down(ss, off, 32);
  if (j == 0) sm[g] = ss;
  __syncthreads();
  // write normalized attention weights back (output `a`)
  float inv[8];
#pragma unroll
  for (int hh = 0; hh < 8; ++hh) inv[hh] = 1.0f / sm[hh];
#pragma unroll
  for (int hh = 0; hh < 8; ++hh) x[hh] = p[hh] * inv[hh];
  ((float4*)L)[t * 2] = make_float4(x[0], x[1], x[2], x[3]);
  ((float4*)L)[t * 2 + 1] = make_float4(x[4], x[5], x[6], x[7]);

  // o accumulation: thread owns output cols (2t, 2t+1); h = t>>5 == g
  const float invh = inv[g];
  const float2* V2 = ((const float2*)(vp + (size_t)b * 256 * 512)) + t;
  float2 acc2; acc2.x = 0.f; acc2.y = 0.f;
#pragma unroll 4
  for (int kk = 0; kk < 256; ++kk) {
    float wgt = tr[g][kk];  // unnormalized p; normalize at the end
    float2 v = V2[(size_t)kk * 256];
    acc2.x += wgt * v.x;
    acc2.y += wgt * v.y;
  }
  acc2.x *= invh;
  acc2.y *= invh;
  ((float2*)(o + (size_t)bq * 512))[t] = acc2;
}

// K6: out = o @ Wo.T + bo
__global__ __launch_bounds__(256) void k6_out(const float* __restrict__ o,
                                              const float* __restrict__ Wo,
                                              const float* __restrict__ bo,
                                              float* __restrict__ out) {
  gemm_tile<1>(o, 512, Wo, 512, out, 512, 512, bo);
}

extern "C" void kernel_launch(void* const* d_in, const int* in_sizes, int n_in,
                              void* d_out, int out_size, void* d_ws,
                              size_t ws_size, hipStream_t stream) {
  const float* query = (const float*)d_in[0];
  const float* key   = (const float*)d_in[1];
  const float* value = (const float*)d_in[2];
  const float* rel   = (const float*)d_in[3];
  const float* Wq    = (const float*)d_in[4];
  const float* Wk    = (const float*)d_in[5];
  // d_in[6] = Wv: unused (reference bug: v = value @ Wq)
  const float* Wr    = (const float*)d_in[7];
  const float* br    = (const float*)d_in[8];
  const float* Wo    = (const float*)d_in[9];
  const float* bo    = (const float*)d_in[10];

  float* out = (float*)d_out;                 // (B,L,E) = 262144 floats
  float* a   = (float*)d_out + (size_t)BL * E;  // (B,L,L,H) = 1048576 floats; also logits scratch

  float* ws = (float*)d_ws;
  float* qp = ws + WS_QP;
  float* kp = ws + WS_KP;
  float* vp = ws + WS_VP;
  float* M  = ws + WS_M;
  float* c  = ws + WS_C;
  float* o  = ws + WS_O;

  // K1: projections (3 GEMMs 512x512x512)
  k1_proj<<<dim3(8, 8, 3), 256, 0, stream>>>(query, key, value, Wq, Wk, qp, kp, vp);
  // K2: M per head (8 GEMMs 512x512x64)
  k2_M<<<dim3(8, 8, 8), 256, 0, stream>>>(kp, Wr, M);
  // K2b: c
  k2b_c<<<dim3(16), 256, 0, stream>>>(kp, br, c);
  // K3: logits = qk + c (into a-region of d_out)
  k3_qk<<<dim3(512), 256, 0, stream>>>(qp, kp, c, a);
  // K4: logits += rel . M  (the HBM-bound pass over 268 MB of relation)
  k4_rel<<<dim3(512), 256, 0, stream>>>(rel, M, a);
  // K5: softmax (in-place -> a) + o = a.vp
  k5_softmax<<<dim3(512), 256, 0, stream>>>(a, vp, o);
  // K6: out = o @ Wo.T + bo
  k6_out<<<dim3(8, 8, 1), 256, 0, stream>>>(o, Wo, bo, out);
}

// Round 3
// 471.723 us; speedup vs baseline: 1.4861x; 1.4861x over previous
//
#include <hip/hip_runtime.h>

#define DEV_INLINE __device__ __forceinline__

typedef float nfloat4 __attribute__((ext_vector_type(4)));  // native vec for nontemporal builtins

// Problem constants (B,L,E,H,HD) = (2,256,512,8,64)
static constexpr int Bb = 2, Ls = 256, E = 512, H = 8;
static constexpr int BL = Bb * Ls;  // 512

// workspace layout in floats
static constexpr size_t WS_QP = 0;
static constexpr size_t WS_KP = WS_QP + (size_t)BL * E;       // 262144
static constexpr size_t WS_VP = WS_KP + (size_t)BL * E;
static constexpr size_t WS_M  = WS_VP + (size_t)BL * E;       // BL*H*E = 2097152
static constexpr size_t WS_C  = WS_M  + (size_t)BL * H * E;   // 4096
static constexpr size_t WS_O  = WS_C  + (size_t)BL * H;       // 262144
// total = 3,149,824 floats = 12.6 MB

DEV_INLINE float dot4f(float4 a, float4 b) {
  return a.x * b.x + a.y * b.y + a.z * b.z + a.w * b.w;
}
DEV_INLINE float dot4n(nfloat4 a, float4 b) {
  return a.x * b.x + a.y * b.y + a.z * b.z + a.w * b.w;
}

// ---------------- generic 64x64 fp32 tiled GEMM core ----------------
template <int TRANSB>
DEV_INLINE void gemm_tile(const float* __restrict__ A, int lda,
                          const float* __restrict__ B, int ldb,
                          float* __restrict__ C, int ldc, int Ksz,
                          const float* __restrict__ bias) {
  __shared__ float As[16][68];
  __shared__ float Bs[16][68];
  const int t = threadIdx.x;
  const int tx = t & 15, ty = t >> 4;
  const int i0 = blockIdx.y * 64, j0 = blockIdx.x * 64;
  float acc[4][4] = {};
  for (int k0 = 0; k0 < Ksz; k0 += 16) {
    {
      const int ka = t & 15, ia = t >> 4;
#pragma unroll
      for (int r = 0; r < 4; ++r)
        As[ka][ia + 16 * r] = A[(size_t)(i0 + ia + 16 * r) * lda + (k0 + ka)];
    }
    if (TRANSB == 0) {
      const int jb = t & 63, kb = t >> 6;
#pragma unroll
      for (int r = 0; r < 4; ++r)
        Bs[kb + 4 * r][jb] = B[(size_t)(k0 + kb + 4 * r) * ldb + (j0 + jb)];
    } else {
      const int kb = t & 15, jb = t >> 4;
#pragma unroll
      for (int r = 0; r < 4; ++r)
        Bs[kb][jb + 16 * r] = B[(size_t)(j0 + jb + 16 * r) * ldb + (k0 + kb)];
    }
    __syncthreads();
#pragma unroll
    for (int kk = 0; kk < 16; ++kk) {
      float4 a4 = *(const float4*)&As[kk][ty * 4];
      float4 b4 = *(const float4*)&Bs[kk][tx * 4];
      acc[0][0] += a4.x * b4.x; acc[0][1] += a4.x * b4.y;
      acc[0][2] += a4.x * b4.z; acc[0][3] += a4.x * b4.w;
      acc[1][0] += a4.y * b4.x; acc[1][1] += a4.y * b4.y;
      acc[1][2] += a4.y * b4.z; acc[1][3] += a4.y * b4.w;
      acc[2][0] += a4.z * b4.x; acc[2][1] += a4.z * b4.y;
      acc[2][2] += a4.z * b4.z; acc[2][3] += a4.z * b4.w;
      acc[3][0] += a4.w * b4.x; acc[3][1] += a4.w * b4.y;
      acc[3][2] += a4.w * b4.z; acc[3][3] += a4.w * b4.w;
    }
    __syncthreads();
  }
#pragma unroll
  for (int r = 0; r < 4; ++r) {
#pragma unroll
    for (int c2 = 0; c2 < 4; ++c2) {
      float v = acc[r][c2];
      if (bias) v += bias[j0 + tx * 4 + c2];
      C[(size_t)(i0 + ty * 4 + r) * ldc + (j0 + tx * 4 + c2)] = v;
    }
  }
}

// K1: qp = query@Wq, kp = key@Wk, vp = value@Wq  (bug preserved: vp uses Wq)
__global__ __launch_bounds__(256) void k1_proj(
    const float* __restrict__ q, const float* __restrict__ k,
    const float* __restrict__ v, const float* __restrict__ Wq,
    const float* __restrict__ Wk, float* __restrict__ qp,
    float* __restrict__ kp, float* __restrict__ vp) {
  const float* A; const float* Bm; float* C;
  switch (blockIdx.z) {
    case 0:  A = q; Bm = Wq; C = qp; break;
    case 1:  A = k; Bm = Wk; C = kp; break;
    default: A = v; Bm = Wq; C = vp; break;
  }
  gemm_tile<0>(A, 512, Bm, 512, C, 512, 512, nullptr);
}

// K2: M[bk, h, e] = sum_d kp[bk, h*64+d] * Wr[h*64+d, e]   (GEMM per head h=z)
__global__ __launch_bounds__(256) void k2_M(const float* __restrict__ kp,
                                            const float* __restrict__ Wr,
                                            float* __restrict__ M) {
  const int h = blockIdx.z;
  gemm_tile<0>(kp + h * 64, 512, Wr + (size_t)h * 64 * 512, 512,
               M + (size_t)h * 512, 4096, 64, nullptr);
}

// K2b: c[bk, h] = sum_d br[h*64+d] * kp[bk, h*64+d]
__global__ __launch_bounds__(256) void k2b_c(const float* __restrict__ kp,
                                             const float* __restrict__ br,
                                             float* __restrict__ c) {
  int idx = blockIdx.x * 256 + threadIdx.x;  // 4096 total
  int bk = idx >> 3, h = idx & 7;
  float s = 0.f;
#pragma unroll 8
  for (int d = 0; d < 64; ++d)
    s += br[h * 64 + d] * kp[(size_t)bk * 512 + h * 64 + d];
  c[idx] = s;
}

// K4 (hot, also does qk + c): for block (b,k,qhalf):
//   logits[b,q,k,h] = sum_e rel[b,q,k,e]*M[b,k,h,e]
//                   + sum_{d in head h} qp[b,q,d]*kp[b,k,d] + c[b,k,h]
// Lane L owns e-slices [4L,4L+4) and [256+4L,256+4L+4): rel loads are fully
// coalesced (1 KB per dwordx4). M cached per-lane (64 VGPR). Per-head partials
// reduced across the wave with a reduce-scatter butterfly (bits 0..2) then
// allreduce (bits 3..5); qk partials folded into the right head bucket via
// 0/1 mask FMAs so the reduction is shared.
__global__ __launch_bounds__(256) void k4_rel(
    const float* __restrict__ rel, const float* __restrict__ Mw,
    const float* __restrict__ qp, const float* __restrict__ kp,
    const float* __restrict__ cbias, float* __restrict__ logits) {
  const int blk = blockIdx.x;       // 1024
  const int bk = blk >> 1;          // 0..511
  const int qh = blk & 1;
  const int b = bk >> 8, k = bk & 255;
  const int t = threadIdx.x, w = t >> 6, lane = t & 63;

  const float* Mbase = Mw + (size_t)bk * 8 * 512;
  float4 m0[8], m1[8];
#pragma unroll
  for (int h = 0; h < 8; ++h) {
    m0[h] = *(const float4*)(Mbase + h * 512 + 4 * lane);
    m1[h] = *(const float4*)(Mbase + h * 512 + 256 + 4 * lane);
  }
  const float* kpr = kp + (size_t)(b * 256 + k) * 512;
  float4 kp0 = *(const float4*)(kpr + 4 * lane);
  float4 kp1 = *(const float4*)(kpr + 256 + 4 * lane);

  // head-ownership masks for qk partials: slice0 -> head lane>>4 (0..3),
  // slice1 -> head 4+(lane>>4)
  const int hq = lane >> 4;
  float w0[4];
#pragma unroll
  for (int h = 0; h < 4; ++h) w0[h] = (hq == h) ? 1.f : 0.f;

  // writer lane h mapping (bit-reversed 3-bit) + c bias
  const int hw = ((lane & 1) << 2) | (lane & 2) | ((lane >> 2) & 1);
  const float cv = cbias[(size_t)(b * 256 + k) * 8 + hw];

  const int q0 = qh * 128 + w;  // this wave's first q; step 4, 32 iters
  const nfloat4* relp =
      (const nfloat4*)(rel) + (((size_t)b * 256 + q0) * 256 + k) * 128;
  const float4* qpp = (const float4*)(qp) + (size_t)(b * 256 + q0) * 128;
  float* lp = logits + (((size_t)b * 256 + q0) * 256 + k) * 8 + hw;
  const bool writer = (lane < 8);
  const size_t REL_STRIDE = (size_t)4 * 256 * 128;  // q += 4, in float4s
  const size_t QP_STRIDE = (size_t)4 * 128;
  const size_t L_STRIDE = (size_t)4 * 256 * 8;

  const bool b0 = (lane & 1) != 0;
  const bool b1 = (lane & 2) != 0;
  const bool b2 = (lane & 4) != 0;

  for (int i = 0; i < 32; ++i) {
    nfloat4 r0 = __builtin_nontemporal_load(&relp[lane]);
    nfloat4 r1 = __builtin_nontemporal_load(&relp[64 + lane]);
    float4 qv0 = qpp[lane];
    float4 qv1 = qpp[64 + lane];

    float acc[8];
#pragma unroll
    for (int h = 0; h < 8; ++h)
      acc[h] = dot4n(r0, m0[h]) + dot4n(r1, m1[h]);
    const float qk0 = dot4f(qv0, kp0);
    const float qk1 = dot4f(qv1, kp1);
#pragma unroll
    for (int h = 0; h < 4; ++h) {
      acc[h] += qk0 * w0[h];
      acc[4 + h] += qk1 * w0[h];
    }

    // reduce-scatter butterfly: bit0 picks h-bit2, bit1 -> h-bit1, bit2 -> h-bit0
    float s[4];
#pragma unroll
    for (int j = 0; j < 4; ++j) {
      float lo = acc[j], hi = acc[j + 4];
      float send = b0 ? lo : hi;
      float keep = b0 ? hi : lo;
      s[j] = keep + __shfl_xor(send, 1);
    }
    float u[2];
#pragma unroll
    for (int j = 0; j < 2; ++j) {
      float lo = s[j], hi = s[j + 2];
      float send = b1 ? lo : hi;
      float keep = b1 ? hi : lo;
      u[j] = keep + __shfl_xor(send, 2);
    }
    {
      float lo = u[0], hi = u[1];
      float send = b2 ? lo : hi;
      float keep = b2 ? hi : lo;
      float v = keep + __shfl_xor(send, 4);
      v += __shfl_xor(v, 8);
      v += __shfl_xor(v, 16);
      v += __shfl_xor(v, 32);
      if (writer) *lp = v + cv;
    }
    relp += REL_STRIDE;
    qpp += QP_STRIDE;
    lp += L_STRIDE;
  }
}

// K5: softmax over k per (b,q,h); writes normalized a in place (d_out region),
// then o[b,q,:] = sum_k a[k,h] * vp[b,k,:]
__global__ __launch_bounds__(256) void k5_softmax(float* __restrict__ logits,
                                                  const float* __restrict__ vp,
                                                  float* __restrict__ o) {
  const int bq = blockIdx.x;
  const int b = bq >> 8;
  const int t = threadIdx.x;
  float* L = logits + (size_t)bq * 2048;
  float4 x0 = ((float4*)L)[t * 2];
  float4 x1 = ((float4*)L)[t * 2 + 1];
  float x[8] = {x0.x, x0.y, x0.z, x0.w, x1.x, x1.y, x1.z, x1.w};
  const float SCALE = 0.125f;  // 1/sqrt(64)
#pragma unroll
  for (int j = 0; j < 8; ++j) x[j] *= SCALE;

  __shared__ float tr[8][272];  // [h][k], stride 272 -> conflict-free
  __shared__ float mx[8], sm[8];
#pragma unroll
  for (int hh = 0; hh < 8; ++hh) tr[hh][t] = x[hh];
  __syncthreads();
  const int g = t >> 5, j = t & 31;
  float m = -1e30f;
#pragma unroll
  for (int i = 0; i < 8; ++i) m = fmaxf(m, tr[g][j + 32 * i]);
#pragma unroll
  for (int off = 16; off >= 1; off >>= 1) m = fmaxf(m, __shfl_down(m, off, 32));
  if (j == 0) mx[g] = m;
  __syncthreads();
  float p[8];
#pragma unroll
  for (int hh = 0; hh < 8; ++hh) p[hh] = __expf(x[hh] - mx[hh]);
#pragma unroll
  for (int hh = 0; hh < 8; ++hh) tr[hh][t] = p[hh];
  __syncthreads();
  float ss = 0.f;
#pragma unroll
  for (int i = 0; i < 8; ++i) ss += tr[g][j + 32 * i];
#pragma unroll
  for (int off = 16; off >= 1; off >>= 1) ss += __shfl_down(ss, off, 32);
  if (j == 0) sm[g] = ss;
  __syncthreads();
  float inv[8];
#pragma unroll
  for (int hh = 0; hh < 8; ++hh) inv[hh] = 1.0f / sm[hh];
#pragma unroll
  for (int hh = 0; hh < 8; ++hh) x[hh] = p[hh] * inv[hh];
  ((float4*)L)[t * 2] = make_float4(x[0], x[1], x[2], x[3]);
  ((float4*)L)[t * 2 + 1] = make_float4(x[4], x[5], x[6], x[7]);

  // o accumulation: thread owns output cols (2t, 2t+1); h = t>>5 == g
  const float invh = inv[g];
  const float2* V2 = ((const float2*)(vp + (size_t)b * 256 * 512)) + t;
  float2 acc2; acc2.x = 0.f; acc2.y = 0.f;
#pragma unroll 8
  for (int kk = 0; kk < 256; ++kk) {
    float wgt = tr[g][kk];  // unnormalized p; normalize at the end
    float2 v = V2[(size_t)kk * 256];
    acc2.x += wgt * v.x;
    acc2.y += wgt * v.y;
  }
  acc2.x *= invh;
  acc2.y *= invh;
  ((float2*)(o + (size_t)bq * 512))[t] = acc2;
}

// K6: out = o @ Wo.T + bo
__global__ __launch_bounds__(256) void k6_out(const float* __restrict__ o,
                                              const float* __restrict__ Wo,
                                              const float* __restrict__ bo,
                                              float* __restrict__ out) {
  gemm_tile<1>(o, 512, Wo, 512, out, 512, 512, bo);
}

extern "C" void kernel_launch(void* const* d_in, const int* in_sizes, int n_in,
                              void* d_out, int out_size, void* d_ws,
                              size_t ws_size, hipStream_t stream) {
  const float* query = (const float*)d_in[0];
  const float* key   = (const float*)d_in[1];
  const float* value = (const float*)d_in[2];
  const float* rel   = (const float*)d_in[3];
  const float* Wq    = (const float*)d_in[4];
  const float* Wk    = (const float*)d_in[5];
  // d_in[6] = Wv: unused (reference bug: v = value @ Wq)
  const float* Wr    = (const float*)d_in[7];
  const float* br    = (const float*)d_in[8];
  const float* Wo    = (const float*)d_in[9];
  const float* bo    = (const float*)d_in[10];

  float* out = (float*)d_out;                   // (B,L,E) = 262144 floats
  float* a   = (float*)d_out + (size_t)BL * E;  // (B,L,L,H); also logits scratch

  float* ws = (float*)d_ws;
  float* qp = ws + WS_QP;
  float* kp = ws + WS_KP;
  float* vp = ws + WS_VP;
  float* M  = ws + WS_M;
  float* c  = ws + WS_C;
  float* o  = ws + WS_O;

  // K1: projections (3 GEMMs 512x512x512)
  k1_proj<<<dim3(8, 8, 3), 256, 0, stream>>>(query, key, value, Wq, Wk, qp, kp, vp);
  // K2: M per head (8 GEMMs 512x512x64)
  k2_M<<<dim3(8, 8, 8), 256, 0, stream>>>(kp, Wr, M);
  // K2b: c
  k2b_c<<<dim3(16), 256, 0, stream>>>(kp, br, c);
  // K4: logits = qk + rel.M + c  (k3 folded in; 1024 blocks for occupancy)
  k4_rel<<<dim3(1024), 256, 0, stream>>>(rel, M, qp, kp, c, a);
  // K5: softmax (in-place -> a) + o = a.vp
  k5_softmax<<<dim3(512), 256, 0, stream>>>(a, vp, o);
  // K6: out = o @ Wo.T + bo
  k6_out<<<dim3(8, 8, 1), 256, 0, stream>>>(o, Wo, bo, out);
}

// Round 4
// 466.855 us; speedup vs baseline: 1.5016x; 1.0104x over previous
//
#include <hip/hip_runtime.h>

#define DEV_INLINE __device__ __forceinline__

typedef float nfloat4 __attribute__((ext_vector_type(4)));  // native vec for nontemporal builtins

// Problem constants (B,L,E,H,HD) = (2,256,512,8,64)
static constexpr int Bb = 2, Ls = 256, E = 512, H = 8;
static constexpr int BL = Bb * Ls;  // 512

// workspace layout in floats
static constexpr size_t WS_QP = 0;
static constexpr size_t WS_KP = WS_QP + (size_t)BL * E;       // 262144
static constexpr size_t WS_VP = WS_KP + (size_t)BL * E;
static constexpr size_t WS_M  = WS_VP + (size_t)BL * E;       // BL*H*E = 2097152
static constexpr size_t WS_C  = WS_M  + (size_t)BL * H * E;   // 4096
static constexpr size_t WS_O  = WS_C  + (size_t)BL * H;       // 262144
// total = 3,149,824 floats = 12.6 MB (ws is 1 GiB; poison cost is harness-fixed)

DEV_INLINE float dot4f(float4 a, float4 b) {
  return a.x * b.x + a.y * b.y + a.z * b.z + a.w * b.w;
}
DEV_INLINE float dot4n(nfloat4 a, float4 b) {
  return a.x * b.x + a.y * b.y + a.z * b.z + a.w * b.w;
}

// ---------------- generic 64x64 fp32 tiled GEMM core ----------------
template <int TRANSB>
DEV_INLINE void gemm_tile(const float* __restrict__ A, int lda,
                          const float* __restrict__ B, int ldb,
                          float* __restrict__ C, int ldc, int Ksz,
                          const float* __restrict__ bias) {
  __shared__ float As[16][68];
  __shared__ float Bs[16][68];
  const int t = threadIdx.x;
  const int tx = t & 15, ty = t >> 4;
  const int i0 = blockIdx.y * 64, j0 = blockIdx.x * 64;
  float acc[4][4] = {};
  for (int k0 = 0; k0 < Ksz; k0 += 16) {
    {
      const int ka = t & 15, ia = t >> 4;
#pragma unroll
      for (int r = 0; r < 4; ++r)
        As[ka][ia + 16 * r] = A[(size_t)(i0 + ia + 16 * r) * lda + (k0 + ka)];
    }
    if (TRANSB == 0) {
      const int jb = t & 63, kb = t >> 6;
#pragma unroll
      for (int r = 0; r < 4; ++r)
        Bs[kb + 4 * r][jb] = B[(size_t)(k0 + kb + 4 * r) * ldb + (j0 + jb)];
    } else {
      const int kb = t & 15, jb = t >> 4;
#pragma unroll
      for (int r = 0; r < 4; ++r)
        Bs[kb][jb + 16 * r] = B[(size_t)(j0 + jb + 16 * r) * ldb + (k0 + kb)];
    }
    __syncthreads();
#pragma unroll
    for (int kk = 0; kk < 16; ++kk) {
      float4 a4 = *(const float4*)&As[kk][ty * 4];
      float4 b4 = *(const float4*)&Bs[kk][tx * 4];
      acc[0][0] += a4.x * b4.x; acc[0][1] += a4.x * b4.y;
      acc[0][2] += a4.x * b4.z; acc[0][3] += a4.x * b4.w;
      acc[1][0] += a4.y * b4.x; acc[1][1] += a4.y * b4.y;
      acc[1][2] += a4.y * b4.z; acc[1][3] += a4.y * b4.w;
      acc[2][0] += a4.z * b4.x; acc[2][1] += a4.z * b4.y;
      acc[2][2] += a4.z * b4.z; acc[2][3] += a4.z * b4.w;
      acc[3][0] += a4.w * b4.x; acc[3][1] += a4.w * b4.y;
      acc[3][2] += a4.w * b4.z; acc[3][3] += a4.w * b4.w;
    }
    __syncthreads();
  }
#pragma unroll
  for (int r = 0; r < 4; ++r) {
#pragma unroll
    for (int c2 = 0; c2 < 4; ++c2) {
      float v = acc[r][c2];
      if (bias) v += bias[j0 + tx * 4 + c2];
      C[(size_t)(i0 + ty * 4 + r) * ldc + (j0 + tx * 4 + c2)] = v;
    }
  }
}

// K1: qp = query@Wq, kp = key@Wk, vp = value@Wq  (bug preserved: vp uses Wq)
__global__ __launch_bounds__(256) void k1_proj(
    const float* __restrict__ q, const float* __restrict__ k,
    const float* __restrict__ v, const float* __restrict__ Wq,
    const float* __restrict__ Wk, float* __restrict__ qp,
    float* __restrict__ kp, float* __restrict__ vp) {
  const float* A; const float* Bm; float* C;
  switch (blockIdx.z) {
    case 0:  A = q; Bm = Wq; C = qp; break;
    case 1:  A = k; Bm = Wk; C = kp; break;
    default: A = v; Bm = Wq; C = vp; break;
  }
  gemm_tile<0>(A, 512, Bm, 512, C, 512, 512, nullptr);
}

// K2: M[bk, h, e] = sum_d kp[bk, h*64+d] * Wr[h*64+d, e]   (GEMM per head h=z)
// Blocks with x==0 also compute c[bk,h] = br_h . kp[bk, h*64:+64] for their rows.
__global__ __launch_bounds__(256) void k2_M(const float* __restrict__ kp,
                                            const float* __restrict__ Wr,
                                            const float* __restrict__ br,
                                            float* __restrict__ M,
                                            float* __restrict__ c) {
  const int h = blockIdx.z;
  if (blockIdx.x == 0 && threadIdx.x < 64) {
    const int row = blockIdx.y * 64 + threadIdx.x;
    float s = 0.f;
    const float* kr = kp + (size_t)row * 512 + h * 64;
    const float* bb = br + h * 64;
#pragma unroll 8
    for (int d = 0; d < 64; ++d) s += bb[d] * kr[d];
    c[(size_t)row * 8 + h] = s;
  }
  gemm_tile<0>(kp + h * 64, 512, Wr + (size_t)h * 64 * 512, 512,
               M + (size_t)h * 512, 4096, 64, nullptr);
}

// K4 (hot, also does qk + c): for block (b,k,qquarter):
//   logits[b,q,k,h] = sum_e rel[b,q,k,e]*M[b,k,h,e]
//                   + sum_{d in head h} qp[b,q,d]*kp[b,k,d] + c[b,k,h]
// Lane L owns e-slices [4L,4L+4) and [256+4L,256+4L+4): rel loads fully
// coalesced (1 KB per dwordx4). M cached per-lane (64 VGPR). Per-head partials
// reduced with a reduce-scatter butterfly; qk folded in via 0/1 mask FMAs.
// 2048 blocks -> hits the ~5 waves/SIMD VGPR occupancy cap.
__global__ __launch_bounds__(256) void k4_rel(
    const float* __restrict__ rel, const float* __restrict__ Mw,
    const float* __restrict__ qp, const float* __restrict__ kp,
    const float* __restrict__ cbias, float* __restrict__ logits) {
  const int blk = blockIdx.x;       // 2048
  const int bk = blk >> 2;          // 0..511
  const int qq = blk & 3;
  const int b = bk >> 8, k = bk & 255;
  const int t = threadIdx.x, w = t >> 6, lane = t & 63;

  const float* Mbase = Mw + (size_t)bk * 8 * 512;
  float4 m0[8], m1[8];
#pragma unroll
  for (int h = 0; h < 8; ++h) {
    m0[h] = *(const float4*)(Mbase + h * 512 + 4 * lane);
    m1[h] = *(const float4*)(Mbase + h * 512 + 256 + 4 * lane);
  }
  const float* kpr = kp + (size_t)(b * 256 + k) * 512;
  float4 kp0 = *(const float4*)(kpr + 4 * lane);
  float4 kp1 = *(const float4*)(kpr + 256 + 4 * lane);

  // head-ownership masks for qk partials: slice0 -> head lane>>4 (0..3),
  // slice1 -> head 4+(lane>>4)
  const int hq = lane >> 4;
  float w0[4];
#pragma unroll
  for (int h = 0; h < 4; ++h) w0[h] = (hq == h) ? 1.f : 0.f;

  // writer lane h mapping (bit-reversed 3-bit) + c bias
  const int hw = ((lane & 1) << 2) | (lane & 2) | ((lane >> 2) & 1);
  const float cv = cbias[(size_t)(b * 256 + k) * 8 + hw];

  const int q0 = qq * 64 + w;  // this wave's first q; step 4, 16 iters
  const nfloat4* relp =
      (const nfloat4*)(rel) + (((size_t)b * 256 + q0) * 256 + k) * 128;
  const float4* qpp = (const float4*)(qp) + (size_t)(b * 256 + q0) * 128;
  float* lp = logits + (((size_t)b * 256 + q0) * 256 + k) * 8 + hw;
  const bool writer = (lane < 8);
  const size_t REL_STRIDE = (size_t)4 * 256 * 128;  // q += 4, in float4s
  const size_t QP_STRIDE = (size_t)4 * 128;
  const size_t L_STRIDE = (size_t)4 * 256 * 8;

  const bool b0 = (lane & 1) != 0;
  const bool b1 = (lane & 2) != 0;
  const bool b2 = (lane & 4) != 0;

  for (int i = 0; i < 16; ++i) {
    nfloat4 r0 = __builtin_nontemporal_load(&relp[lane]);
    nfloat4 r1 = __builtin_nontemporal_load(&relp[64 + lane]);
    float4 qv0 = qpp[lane];
    float4 qv1 = qpp[64 + lane];

    float acc[8];
#pragma unroll
    for (int h = 0; h < 8; ++h)
      acc[h] = dot4n(r0, m0[h]) + dot4n(r1, m1[h]);
    const float qk0 = dot4f(qv0, kp0);
    const float qk1 = dot4f(qv1, kp1);
#pragma unroll
    for (int h = 0; h < 4; ++h) {
      acc[h] += qk0 * w0[h];
      acc[4 + h] += qk1 * w0[h];
    }

    // reduce-scatter butterfly: bit0 picks h-bit2, bit1 -> h-bit1, bit2 -> h-bit0
    float s[4];
#pragma unroll
    for (int j = 0; j < 4; ++j) {
      float lo = acc[j], hi = acc[j + 4];
      float send = b0 ? lo : hi;
      float keep = b0 ? hi : lo;
      s[j] = keep + __shfl_xor(send, 1);
    }
    float u[2];
#pragma unroll
    for (int j = 0; j < 2; ++j) {
      float lo = s[j], hi = s[j + 2];
      float send = b1 ? lo : hi;
      float keep = b1 ? hi : lo;
      u[j] = keep + __shfl_xor(send, 2);
    }
    {
      float lo = u[0], hi = u[1];
      float send = b2 ? lo : hi;
      float keep = b2 ? hi : lo;
      float v = keep + __shfl_xor(send, 4);
      v += __shfl_xor(v, 8);
      v += __shfl_xor(v, 16);
      v += __shfl_xor(v, 32);
      if (writer) *lp = v + cv;
    }
    relp += REL_STRIDE;
    qpp += QP_STRIDE;
    lp += L_STRIDE;
  }
}

// K5: softmax over k per (b,q,h); writes normalized a in place (d_out region),
// then o[b,q,:] = sum_k a[k,h] * vp[b,k,:]
__global__ __launch_bounds__(256) void k5_softmax(float* __restrict__ logits,
                                                  const float* __restrict__ vp,
                                                  float* __restrict__ o) {
  const int bq = blockIdx.x;
  const int b = bq >> 8;
  const int t = threadIdx.x;
  float* L = logits + (size_t)bq * 2048;
  float4 x0 = ((float4*)L)[t * 2];
  float4 x1 = ((float4*)L)[t * 2 + 1];
  float x[8] = {x0.x, x0.y, x0.z, x0.w, x1.x, x1.y, x1.z, x1.w};
  const float SCALE = 0.125f;  // 1/sqrt(64)
#pragma unroll
  for (int j = 0; j < 8; ++j) x[j] *= SCALE;

  __shared__ float tr[8][272];  // [h][k], stride 272 -> conflict-free
  __shared__ float mx[8], sm[8];
#pragma unroll
  for (int hh = 0; hh < 8; ++hh) tr[hh][t] = x[hh];
  __syncthreads();
  const int g = t >> 5, j = t & 31;
  float m = -1e30f;
#pragma unroll
  for (int i = 0; i < 8; ++i) m = fmaxf(m, tr[g][j + 32 * i]);
#pragma unroll
  for (int off = 16; off >= 1; off >>= 1) m = fmaxf(m, __shfl_down(m, off, 32));
  if (j == 0) mx[g] = m;
  __syncthreads();
  float p[8];
#pragma unroll
  for (int hh = 0; hh < 8; ++hh) p[hh] = __expf(x[hh] - mx[hh]);
#pragma unroll
  for (int hh = 0; hh < 8; ++hh) tr[hh][t] = p[hh];
  __syncthreads();
  float ss = 0.f;
#pragma unroll
  for (int i = 0; i < 8; ++i) ss += tr[g][j + 32 * i];
#pragma unroll
  for (int off = 16; off >= 1; off >>= 1) ss += __shfl_down(ss, off, 32);
  if (j == 0) sm[g] = ss;
  __syncthreads();
  float inv[8];
#pragma unroll
  for (int hh = 0; hh < 8; ++hh) inv[hh] = 1.0f / sm[hh];
#pragma unroll
  for (int hh = 0; hh < 8; ++hh) x[hh] = p[hh] * inv[hh];
  ((float4*)L)[t * 2] = make_float4(x[0], x[1], x[2], x[3]);
  ((float4*)L)[t * 2 + 1] = make_float4(x[4], x[5], x[6], x[7]);

  // o accumulation: thread owns output cols (2t, 2t+1); h = t>>5 == g
  const float invh = inv[g];
  const float2* V2 = ((const float2*)(vp + (size_t)b * 256 * 512)) + t;
  float2 acc2; acc2.x = 0.f; acc2.y = 0.f;
#pragma unroll 8
  for (int kk = 0; kk < 256; ++kk) {
    float wgt = tr[g][kk];  // unnormalized p; normalize at the end
    float2 v = V2[(size_t)kk * 256];
    acc2.x += wgt * v.x;
    acc2.y += wgt * v.y;
  }
  acc2.x *= invh;
  acc2.y *= invh;
  ((float2*)(o + (size_t)bq * 512))[t] = acc2;
}

// K6: out = o @ Wo.T + bo
__global__ __launch_bounds__(256) void k6_out(const float* __restrict__ o,
                                              const float* __restrict__ Wo,
                                              const float* __restrict__ bo,
                                              float* __restrict__ out) {
  gemm_tile<1>(o, 512, Wo, 512, out, 512, 512, bo);
}

extern "C" void kernel_launch(void* const* d_in, const int* in_sizes, int n_in,
                              void* d_out, int out_size, void* d_ws,
                              size_t ws_size, hipStream_t stream) {
  const float* query = (const float*)d_in[0];
  const float* key   = (const float*)d_in[1];
  const float* value = (const float*)d_in[2];
  const float* rel   = (const float*)d_in[3];
  const float* Wq    = (const float*)d_in[4];
  const float* Wk    = (const float*)d_in[5];
  // d_in[6] = Wv: unused (reference bug: v = value @ Wq)
  const float* Wr    = (const float*)d_in[7];
  const float* br    = (const float*)d_in[8];
  const float* Wo    = (const float*)d_in[9];
  const float* bo    = (const float*)d_in[10];

  float* out = (float*)d_out;                   // (B,L,E) = 262144 floats
  float* a   = (float*)d_out + (size_t)BL * E;  // (B,L,L,H); also logits scratch

  float* ws = (float*)d_ws;
  float* qp = ws + WS_QP;
  float* kp = ws + WS_KP;
  float* vp = ws + WS_VP;
  float* M  = ws + WS_M;
  float* c  = ws + WS_C;
  float* o  = ws + WS_O;

  // K1: projections (3 GEMMs 512x512x512)
  k1_proj<<<dim3(8, 8, 3), 256, 0, stream>>>(query, key, value, Wq, Wk, qp, kp, vp);
  // K2: M per head (8 GEMMs 512x512x64) + c bias folded in
  k2_M<<<dim3(8, 8, 8), 256, 0, stream>>>(kp, Wr, br, M, c);
  // K4: logits = qk + rel.M + c  (2048 blocks -> occupancy cap)
  k4_rel<<<dim3(2048), 256, 0, stream>>>(rel, M, qp, kp, c, a);
  // K5: softmax (in-place -> a) + o = a.vp
  k5_softmax<<<dim3(512), 256, 0, stream>>>(a, vp, o);
  // K6: out = o @ Wo.T + bo
  k6_out<<<dim3(8, 8, 1), 256, 0, stream>>>(o, Wo, bo, out);
}